// Round 9
// baseline (519.631 us; speedup 1.0000x reference)
//
#include <hip/hip_runtime.h>
#include <math.h>

#define DD 128

typedef __attribute__((ext_vector_type(8))) short short8;   // 8 x bf16 bits
typedef __attribute__((ext_vector_type(4))) float f32x4;
typedef __attribute__((ext_vector_type(4))) _Float16 f16x4;

__device__ inline short bf16hi(float x) {
  unsigned u = __float_as_uint(x);
  unsigned r = u + 0x7fffu + ((u >> 16) & 1u);  // RTNE
  return (short)(r >> 16);
}
__device__ inline float bf16tof(short h) {
  return __uint_as_float(((unsigned)(unsigned short)h) << 16);
}
__device__ inline void split2(float x, short& hi, short& lo) {  // RTNE (weights only)
  hi = bf16hi(x);
  float rem = x - bf16tof(hi);
  lo = bf16hi(rem);
}
__device__ inline void splitT(float x, short& hi, short& lo) {  // truncation (cheap)
  unsigned u = __float_as_uint(x);
  hi = (short)(u >> 16);
  float rem = x - __uint_as_float(u & 0xffff0000u);
  lo = (short)(__float_as_uint(rem) >> 16);
}

// ---------------- small helper kernels ----------------
__global__ __launch_bounds__(128) void zero128_kernel(float* p) { p[threadIdx.x] = 0.f; }

__global__ __launch_bounds__(256) void colsum_kernel(const float* __restrict__ x,
                                                     float* __restrict__ colsum, int N) {
  int col = threadIdx.x & 127;
  int part = (blockIdx.x * blockDim.x + threadIdx.x) >> 7;
  int nparts = (gridDim.x * blockDim.x) >> 7;
  float s = 0.f;
  for (int r = part; r < N; r += nparts) s += x[(size_t)r * DD + col];
  atomicAdd(&colsum[col], s);
}

__global__ __launch_bounds__(128) void glb_kernel(const float* __restrict__ colsum,
                                                  const float* __restrict__ glb_W,
                                                  const float* __restrict__ glb_b,
                                                  float* __restrict__ g, float invN) {
  __shared__ float m[DD];
  int j = threadIdx.x;
  m[j] = colsum[j] * invN;
  __syncthreads();
  float s = glb_b[j];
#pragma unroll 8
  for (int k = 0; k < DD; ++k) s = fmaf(m[k], glb_W[k * DD + j], s);
  g[j] = fmaxf(s, 0.f);
}

// W2U = msg_W2 @ upd_W1[128:256] (128x128), v2 = msg_b2 @ upd_W1[128:256] (128)
__global__ __launch_bounds__(256) void wprep_kernel(const float* __restrict__ msg_W2,
                                                    const float* __restrict__ msg_b2,
                                                    const float* __restrict__ upd_W1,
                                                    float* __restrict__ W2U,
                                                    float* __restrict__ v2) {
  int o = blockIdx.x * 256 + threadIdx.x;
  if (o < 16384) {
    int r = o >> 7, c = o & 127;
    float s = 0.f;
#pragma unroll 8
    for (int j = 0; j < 128; ++j) s = fmaf(msg_W2[r * 128 + j], upd_W1[(128 + j) * 128 + c], s);
    W2U[o] = s;
  } else if (o < 16512) {
    int c = o - 16384;
    float s = 0.f;
#pragma unroll 8
    for (int j = 0; j < 128; ++j) s = fmaf(msg_b2[j], upd_W1[(128 + j) * 128 + c], s);
    v2[c] = s;
  }
}

// ---------------- CSR build: histogram -> parallel scan -> scatter ----------------
__global__ __launch_bounds__(256) void hist_kernel(const int* __restrict__ dst,
                                                   int* __restrict__ rowptr, int E) {
  for (int e = blockIdx.x * blockDim.x + threadIdx.x; e < E; e += gridDim.x * blockDim.x)
    atomicAdd(&rowptr[dst[e] + 1], 1);
}

__global__ __launch_bounds__(1024) void scan1_kernel(int* __restrict__ a,
                                                     int* __restrict__ bsum, int n) {
  __shared__ int buf[1024];
  const int tid = threadIdx.x;
  int i = blockIdx.x * 1024 + tid;
  buf[tid] = (i < n) ? a[i] : 0;
  __syncthreads();
#pragma unroll
  for (int off = 1; off < 1024; off <<= 1) {
    int t = (tid >= off) ? buf[tid - off] : 0;
    __syncthreads();
    buf[tid] += t;
    __syncthreads();
  }
  if (i < n) a[i] = buf[tid];
  if (tid == 1023) bsum[blockIdx.x] = buf[1023];
}

__global__ __launch_bounds__(1024) void scan2_kernel(int* __restrict__ a, int n) {
  __shared__ int buf[1024];
  const int tid = threadIdx.x;
  buf[tid] = (tid < n) ? a[tid] : 0;
  __syncthreads();
#pragma unroll
  for (int off = 1; off < 1024; off <<= 1) {
    int t = (tid >= off) ? buf[tid - off] : 0;
    __syncthreads();
    buf[tid] += t;
    __syncthreads();
  }
  if (tid < n) a[tid] = buf[tid];
}

__global__ __launch_bounds__(1024) void scan3_kernel(int* __restrict__ a,
                                                     const int* __restrict__ bsum, int n) {
  int b = blockIdx.x + 1;
  int i = b * 1024 + threadIdx.x;
  if (i < n) a[i] += bsum[b - 1];
}

__global__ __launch_bounds__(256) void scatter_kernel(const int* __restrict__ src,
                                                      const int* __restrict__ dst,
                                                      int* __restrict__ cursor,
                                                      int* __restrict__ sortedSrc, int E) {
  for (int e = blockIdx.x * blockDim.x + threadIdx.x; e < E; e += gridDim.x * blockDim.x) {
    int pos = atomicAdd(&cursor[dst[e]], 1);
    sortedSrc[pos] = src[e];
  }
}

// ---------------- weight prep: all frag-major hi/lo ----------------
__global__ __launch_bounds__(256) void conv_kernel(
    const float* __restrict__ msg_W1, const float* __restrict__ att_W1,
    const float* __restrict__ upd_W1, const float* __restrict__ upd_W2,
    const float* __restrict__ W2U,
    short* __restrict__ WbigF, short* __restrict__ U1F, short* __restrict__ U2F) {
  int i = blockIdx.x * 256 + threadIdx.x;  // 0 .. 28671
  if (i < 16384) {
    int lane = i & 63, p = (i >> 6) & 1, n = (i >> 7) & 31, c = i >> 12;
    int col = n * 16 + (lane & 15);
#pragma unroll
    for (int j = 0; j < 8; ++j) {
      int k = c * 32 + ((lane >> 4) & 3) * 8 + j;
      float v;
      if (col < 128)      v = msg_W1[k * 128 + col];
      else if (col < 256) v = att_W1[k * 128 + (col - 128)];
      else if (col < 384) v = msg_W1[(k + 128) * 128 + (col - 256)];
      else                v = att_W1[(k + 128) * 128 + (col - 384)];
      short hi, lo; splitT(v, hi, lo);
      WbigF[(size_t)i * 8 + j] = p ? lo : hi;
    }
  } else if (i < 24576) {
    int gI = i - 16384;  // 8192 entries
    int lane = gI & 63, p = (gI >> 6) & 1, n = (gI >> 7) & 7, c = gI >> 10;  // c in [0,8)
    int col = n * 16 + (lane & 15);
#pragma unroll
    for (int j = 0; j < 8; ++j) {
      int k = c * 32 + ((lane >> 4) & 3) * 8 + j;
      float v = (k < 128) ? upd_W1[k * 128 + col] : W2U[(k - 128) * 128 + col];
      short hi, lo; split2(v, hi, lo);
      U1F[(size_t)gI * 8 + j] = p ? lo : hi;
    }
  } else {
    int gI = i - 24576;  // 4096 entries
    int lane = gI & 63, p = (gI >> 6) & 1, n = (gI >> 7) & 7, c = gI >> 10;  // c in [0,4)
    int col = n * 16 + (lane & 15);
#pragma unroll
    for (int j = 0; j < 8; ++j) {
      int k = c * 32 + ((lane >> 4) & 3) * 8 + j;
      float v = upd_W2[k * 128 + col];
      short hi, lo; split2(v, hi, lo);
      U2F[(size_t)gI * 8 + j] = p ? lo : hi;
    }
  }
}

// ---------------- Z-prep GEMM (step 0): Z[N x 512] fp16 = h @ Wbig + bias ----
__global__ __launch_bounds__(256, 2) void zprep_kernel(
    const float* __restrict__ h, const short* __restrict__ WbigF,
    const float* __restrict__ msg_b1, const float* __restrict__ att_b1,
    _Float16* __restrict__ Z, int N) {
  const int tid = threadIdx.x;
  const int w = tid >> 6;
  const int lane = tid & 63;
  const int m16 = lane & 15, q = lane >> 4;
  const int r0 = blockIdx.x * 32;

  f32x4 acc[2][8];
#pragma unroll
  for (int nt = 0; nt < 8; ++nt) {
    int col = w * 128 + nt * 16 + m16;
    float b = (col < 128) ? msg_b1[col] : ((col < 256) ? att_b1[col - 128] : 0.f);
    acc[0][nt] = (f32x4){b, b, b, b};
    acc[1][nt] = (f32x4){b, b, b, b};
  }

  for (int c = 0; c < 4; ++c) {
    short8 ah[2], al[2];
#pragma unroll
    for (int mt = 0; mt < 2; ++mt) {
      int row = min(r0 + mt * 16 + m16, N - 1);
      const float* p = h + (size_t)row * DD + c * 32 + q * 8;
      float4 v0 = *(const float4*)p;
      float4 v1 = *(const float4*)(p + 4);
      float f[8] = {v0.x, v0.y, v0.z, v0.w, v1.x, v1.y, v1.z, v1.w};
#pragma unroll
      for (int j = 0; j < 8; ++j) { short hi, lo; splitT(f[j], hi, lo); ah[mt][j] = hi; al[mt][j] = lo; }
    }
#pragma unroll
    for (int nt = 0; nt < 8; ++nt) {
      int ng = w * 8 + nt;
      const short* bp = WbigF + ((size_t)((c * 32 + ng) * 2) * 64 + lane) * 8;
      short8 bh = *(const short8*)bp;
      short8 bl = *(const short8*)(bp + 512);
#pragma unroll
      for (int mt = 0; mt < 2; ++mt) {
        acc[mt][nt] = __builtin_amdgcn_mfma_f32_16x16x32_bf16(ah[mt], bh, acc[mt][nt], 0, 0, 0);
        acc[mt][nt] = __builtin_amdgcn_mfma_f32_16x16x32_bf16(al[mt], bh, acc[mt][nt], 0, 0, 0);
        acc[mt][nt] = __builtin_amdgcn_mfma_f32_16x16x32_bf16(ah[mt], bl, acc[mt][nt], 0, 0, 0);
      }
    }
  }

#pragma unroll
  for (int mt = 0; mt < 2; ++mt)
#pragma unroll
    for (int r = 0; r < 4; ++r) {
      int row = r0 + mt * 16 + q * 4 + r;
      if (row < N) {
#pragma unroll
        for (int nt = 0; nt < 8; ++nt) {
          int col = w * 128 + nt * 16 + m16;
          Z[(size_t)row * 512 + col] = (_Float16)acc[mt][nt][r];
        }
      }
    }
}

// ---------------- CSR aggregation (no atomics; all-fp16 Z) ----------------
__global__ __launch_bounds__(256) void aggcsr_kernel(
    const _Float16* __restrict__ Z, const int* __restrict__ rowptr,
    const int* __restrict__ sortedSrc, const float* __restrict__ att_W2,
    const float* __restrict__ att_b2, float* __restrict__ aggH,
    float* __restrict__ aggA, int N) {
  const int node = blockIdx.x * 8 + (threadIdx.x >> 5);
  const int c = threadIdx.x & 31;
  if (node >= N) return;

  const float4 aw = *(const float4*)(att_W2 + 4 * c);
  const float ab2 = att_b2[0];
  const _Float16* Zn = Z + (size_t)node * 512 + 256;
  f16x4 dmh = *(const f16x4*)(Zn + 4 * c);
  f16x4 dah = *(const f16x4*)(Zn + 128 + 4 * c);
  float dm[4] = {(float)dmh[0], (float)dmh[1], (float)dmh[2], (float)dmh[3]};
  float da[4] = {(float)dah[0], (float)dah[1], (float)dah[2], (float)dah[3]};

  float aH0 = 0.f, aH1 = 0.f, aH2 = 0.f, aH3 = 0.f, aA = 0.f;
  const int b = rowptr[node], e = rowptr[node + 1];

  int i = b;
  for (; i + 1 < e; i += 2) {
    int s0 = sortedSrc[i], s1 = sortedSrc[i + 1];
    const _Float16* Z0 = Z + (size_t)s0 * 512 + 4 * c;
    const _Float16* Z1 = Z + (size_t)s1 * 512 + 4 * c;
    f16x4 m0 = *(const f16x4*)Z0, a0 = *(const f16x4*)(Z0 + 128);
    f16x4 m1 = *(const f16x4*)Z1, a1 = *(const f16x4*)(Z1 + 128);

    float h0[4], h1[4];
    h0[0] = fmaxf((float)m0[0] + dm[0], 0.f); h0[1] = fmaxf((float)m0[1] + dm[1], 0.f);
    h0[2] = fmaxf((float)m0[2] + dm[2], 0.f); h0[3] = fmaxf((float)m0[3] + dm[3], 0.f);
    h1[0] = fmaxf((float)m1[0] + dm[0], 0.f); h1[1] = fmaxf((float)m1[1] + dm[1], 0.f);
    h1[2] = fmaxf((float)m1[2] + dm[2], 0.f); h1[3] = fmaxf((float)m1[3] + dm[3], 0.f);

    float p0 = fmaf(fmaxf((float)a0[0] + da[0], 0.f), aw.x,
               fmaf(fmaxf((float)a0[1] + da[1], 0.f), aw.y,
               fmaf(fmaxf((float)a0[2] + da[2], 0.f), aw.z,
                    fmaxf((float)a0[3] + da[3], 0.f) * aw.w)));
    float p1 = fmaf(fmaxf((float)a1[0] + da[0], 0.f), aw.x,
               fmaf(fmaxf((float)a1[1] + da[1], 0.f), aw.y,
               fmaf(fmaxf((float)a1[2] + da[2], 0.f), aw.z,
                    fmaxf((float)a1[3] + da[3], 0.f) * aw.w)));
#pragma unroll
    for (int off = 1; off < 32; off <<= 1) {
      p0 += __shfl_xor(p0, off);
      p1 += __shfl_xor(p1, off);
    }
    float t0 = 1.f / (1.f + expf(-(p0 + ab2)));
    float t1 = 1.f / (1.f + expf(-(p1 + ab2)));
    aA += t0 + t1;
    aH0 = fmaf(t0, h0[0], fmaf(t1, h1[0], aH0));
    aH1 = fmaf(t0, h0[1], fmaf(t1, h1[1], aH1));
    aH2 = fmaf(t0, h0[2], fmaf(t1, h1[2], aH2));
    aH3 = fmaf(t0, h0[3], fmaf(t1, h1[3], aH3));
  }
  if (i < e) {
    int s0 = sortedSrc[i];
    const _Float16* Z0 = Z + (size_t)s0 * 512 + 4 * c;
    f16x4 m0 = *(const f16x4*)Z0, a0 = *(const f16x4*)(Z0 + 128);
    float h00 = fmaxf((float)m0[0] + dm[0], 0.f), h01 = fmaxf((float)m0[1] + dm[1], 0.f);
    float h02 = fmaxf((float)m0[2] + dm[2], 0.f), h03 = fmaxf((float)m0[3] + dm[3], 0.f);
    float p0 = fmaf(fmaxf((float)a0[0] + da[0], 0.f), aw.x,
               fmaf(fmaxf((float)a0[1] + da[1], 0.f), aw.y,
               fmaf(fmaxf((float)a0[2] + da[2], 0.f), aw.z,
                    fmaxf((float)a0[3] + da[3], 0.f) * aw.w)));
#pragma unroll
    for (int off = 1; off < 32; off <<= 1) p0 += __shfl_xor(p0, off);
    float t0 = 1.f / (1.f + expf(-(p0 + ab2)));
    aA += t0;
    aH0 = fmaf(t0, h00, aH0);
    aH1 = fmaf(t0, h01, aH1);
    aH2 = fmaf(t0, h02, aH2);
    aH3 = fmaf(t0, h03, aH3);
  }

  *(float4*)(aggH + (size_t)node * DD + 4 * c) = (float4){aH0, aH1, aH2, aH3};
  if (c == 0) aggA[node] = aA;
}

// ---------------- node update: column-split waves (Mr=4, 12 MFMA per B-pair) ----
// out = relu(h@U1top + aggH@W2U + aggA (x) v2 + upd_b1) @ U2 + upd_b2 + h + g
// Wave w owns cols [32w, 32w+32) in GEMM1/GEMM2, all 64 rows of the block.
// DOZ: additionally Z = out @ Wbig for this block's 64 rows (fp16), wave w -> 128 cols.
template <int DOZ>
__global__ __launch_bounds__(256, 3) void node_mfma_kernel(
    const float* __restrict__ h, const float* __restrict__ aggH,
    const float* __restrict__ aggA, const float* __restrict__ v2,
    const short* __restrict__ U1F, const short* __restrict__ U2F,
    const float* __restrict__ upd_b1, const float* __restrict__ upd_b2,
    const float* __restrict__ g, float* __restrict__ out, int N,
    const short* __restrict__ WbigF, const float* __restrict__ msg_b1,
    const float* __restrict__ att_b1, _Float16* __restrict__ Z) {
  __shared__ __align__(16) char smemraw[33792];
  unsigned* HID32 = (unsigned*)smemraw;  // 64 x 132 packed (hi<<16 | lo)
  float* OUTs = (float*)smemraw;         // 64 x 132 fp32 (DOZ overlay)

  const int tid = threadIdx.x;
  const int w = tid >> 6;
  const int lane = tid & 63;
  const int m16 = lane & 15;
  const int q = lane >> 4;
  const int n0 = blockIdx.x * 64;

  int rowA[4];
#pragma unroll
  for (int mt = 0; mt < 4; ++mt) rowA[mt] = min(n0 + mt * 16 + m16, N - 1);

  const int colW = w * 32 + m16;  // + nt2*16

  // ---- GEMM1: cols [32w,32w+32), rows 0..64 ----
  f32x4 acc1[2][4];
#pragma unroll
  for (int nt2 = 0; nt2 < 2; ++nt2) {
    float b = upd_b1[colW + nt2 * 16];
#pragma unroll
    for (int mt = 0; mt < 4; ++mt) acc1[nt2][mt] = (f32x4){b, b, b, b};
  }

#pragma unroll
  for (int c = 0; c < 8; ++c) {
    short8 ah[4], al[4];
#pragma unroll
    for (int mt = 0; mt < 4; ++mt) {
      const float* base = (c < 4 ? h + (size_t)rowA[mt] * DD + c * 32
                                 : aggH + (size_t)rowA[mt] * DD + (c - 4) * 32) + q * 8;
      float4 v0 = *(const float4*)base;
      float4 v1 = *(const float4*)(base + 4);
      float f[8] = {v0.x, v0.y, v0.z, v0.w, v1.x, v1.y, v1.z, v1.w};
#pragma unroll
      for (int j = 0; j < 8; ++j) { short hi, lo; splitT(f[j], hi, lo); ah[mt][j] = hi; al[mt][j] = lo; }
    }
#pragma unroll
    for (int nt2 = 0; nt2 < 2; ++nt2) {
      int pair = c * 8 + w * 2 + nt2;
      const short* bp = U1F + ((size_t)(pair * 2) * 64 + lane) * 8;
      short8 bh = *(const short8*)bp;
      short8 bl = *(const short8*)(bp + 512);
#pragma unroll
      for (int mt = 0; mt < 4; ++mt) {
        acc1[nt2][mt] = __builtin_amdgcn_mfma_f32_16x16x32_bf16(ah[mt], bh, acc1[nt2][mt], 0, 0, 0);
        acc1[nt2][mt] = __builtin_amdgcn_mfma_f32_16x16x32_bf16(al[mt], bh, acc1[nt2][mt], 0, 0, 0);
        acc1[nt2][mt] = __builtin_amdgcn_mfma_f32_16x16x32_bf16(ah[mt], bl, acc1[nt2][mt], 0, 0, 0);
      }
    }
  }

  // aggA fold + relu + pack into HID32
  {
    float v2c[2] = {v2[colW], v2[colW + 16]};
#pragma unroll
    for (int mt = 0; mt < 4; ++mt) {
      float aAv[4];
#pragma unroll
      for (int r = 0; r < 4; ++r) aAv[r] = aggA[min(n0 + mt * 16 + q * 4 + r, N - 1)];
#pragma unroll
      for (int nt2 = 0; nt2 < 2; ++nt2) {
        int col = colW + nt2 * 16;
#pragma unroll
        for (int r = 0; r < 4; ++r) {
          float v = fmaxf(fmaf(aAv[r], v2c[nt2], acc1[nt2][mt][r]), 0.f);
          short hi, lo; splitT(v, hi, lo);
          HID32[(mt * 16 + q * 4 + r) * 132 + col] =
              (((unsigned)(unsigned short)hi) << 16) | (unsigned)(unsigned short)lo;
        }
      }
    }
  }
  __syncthreads();

  // ---- GEMM2: cols [32w,32w+32), rows 0..64, K=128 from HID ----
  f32x4 acc2[2][4];
#pragma unroll
  for (int nt2 = 0; nt2 < 2; ++nt2) {
    float b = upd_b2[colW + nt2 * 16];
#pragma unroll
    for (int mt = 0; mt < 4; ++mt) acc2[nt2][mt] = (f32x4){b, b, b, b};
  }

#pragma unroll
  for (int c2 = 0; c2 < 4; ++c2) {
    short8 a2h[4], a2l[4];
#pragma unroll
    for (int mt = 0; mt < 4; ++mt) {
      const unsigned* hp = &HID32[(mt * 16 + m16) * 132 + c2 * 32 + q * 8];
      uint4 u0 = *(const uint4*)hp;
      uint4 u1 = *(const uint4*)(hp + 4);
      unsigned u[8] = {u0.x, u0.y, u0.z, u0.w, u1.x, u1.y, u1.z, u1.w};
#pragma unroll
      for (int j = 0; j < 8; ++j) {
        a2h[mt][j] = (short)(u[j] >> 16);
        a2l[mt][j] = (short)(u[j] & 0xffffu);
      }
    }
#pragma unroll
    for (int nt2 = 0; nt2 < 2; ++nt2) {
      int pair = c2 * 8 + w * 2 + nt2;
      const short* bp = U2F + ((size_t)(pair * 2) * 64 + lane) * 8;
      short8 bh = *(const short8*)bp;
      short8 bl = *(const short8*)(bp + 512);
#pragma unroll
      for (int mt = 0; mt < 4; ++mt) {
        acc2[nt2][mt] = __builtin_amdgcn_mfma_f32_16x16x32_bf16(a2h[mt], bh, acc2[nt2][mt], 0, 0, 0);
        acc2[nt2][mt] = __builtin_amdgcn_mfma_f32_16x16x32_bf16(a2l[mt], bh, acc2[nt2][mt], 0, 0, 0);
        acc2[nt2][mt] = __builtin_amdgcn_mfma_f32_16x16x32_bf16(a2h[mt], bl, acc2[nt2][mt], 0, 0, 0);
      }
    }
  }

  // epilogue: out = acc2 + h + g  (DOZ: stage into LDS for fused Z-prep)
  if (DOZ) __syncthreads();  // all HID32 reads done before OUTs overlay
  {
    float gc[2] = {g[colW], g[colW + 16]};
#pragma unroll
    for (int mt = 0; mt < 4; ++mt) {
#pragma unroll
      for (int r = 0; r < 4; ++r) {
        int rowN = n0 + mt * 16 + q * 4 + r;
        int rc = min(rowN, N - 1);
#pragma unroll
        for (int nt2 = 0; nt2 < 2; ++nt2) {
          int col = colW + nt2 * 16;
          float v = acc2[nt2][mt][r] + h[(size_t)rc * DD + col] + gc[nt2];
          if (DOZ) OUTs[(mt * 16 + q * 4 + r) * 132 + col] = v;
          if (rowN < N) out[(size_t)rowN * DD + col] = v;
        }
      }
    }
  }

  if (DOZ) {
    __syncthreads();
    // Z-GEMM for this block's 64 rows: wave w -> cols [128w, 128w+128)
#pragma unroll
    for (int half = 0; half < 2; ++half) {
      f32x4 zacc[4][4];
#pragma unroll
      for (int nt = 0; nt < 4; ++nt) {
        int col = w * 128 + half * 64 + nt * 16 + m16;
        float b = (col < 128) ? msg_b1[col] : ((col < 256) ? att_b1[col - 128] : 0.f);
#pragma unroll
        for (int mt = 0; mt < 4; ++mt) zacc[mt][nt] = (f32x4){b, b, b, b};
      }
      for (int c = 0; c < 4; ++c) {
        short8 ah[4], al[4];
#pragma unroll
        for (int mt = 0; mt < 4; ++mt) {
          const float* p = OUTs + (mt * 16 + m16) * 132 + c * 32 + q * 8;
          float4 v0 = *(const float4*)p;
          float4 v1 = *(const float4*)(p + 4);
          float f[8] = {v0.x, v0.y, v0.z, v0.w, v1.x, v1.y, v1.z, v1.w};
#pragma unroll
          for (int j = 0; j < 8; ++j) {
            short hi, lo; splitT(f[j], hi, lo); ah[mt][j] = hi; al[mt][j] = lo;
          }
        }
#pragma unroll
        for (int nt = 0; nt < 4; ++nt) {
          int ng = w * 8 + half * 4 + nt;
          const short* bp = WbigF + ((size_t)((c * 32 + ng) * 2) * 64 + lane) * 8;
          short8 bh = *(const short8*)bp;
          short8 bl = *(const short8*)(bp + 512);
#pragma unroll
          for (int mt = 0; mt < 4; ++mt) {
            zacc[mt][nt] = __builtin_amdgcn_mfma_f32_16x16x32_bf16(ah[mt], bh, zacc[mt][nt], 0, 0, 0);
            zacc[mt][nt] = __builtin_amdgcn_mfma_f32_16x16x32_bf16(al[mt], bh, zacc[mt][nt], 0, 0, 0);
            zacc[mt][nt] = __builtin_amdgcn_mfma_f32_16x16x32_bf16(ah[mt], bl, zacc[mt][nt], 0, 0, 0);
          }
        }
      }
#pragma unroll
      for (int mt = 0; mt < 4; ++mt)
#pragma unroll
        for (int r = 0; r < 4; ++r) {
          int row = n0 + mt * 16 + q * 4 + r;
          if (row < N) {
#pragma unroll
            for (int nt = 0; nt < 4; ++nt) {
              int col = w * 128 + half * 64 + nt * 16 + m16;
              Z[(size_t)row * 512 + col] = (_Float16)zacc[mt][nt][r];
            }
          }
        }
    }
  }
}

extern "C" void kernel_launch(void* const* d_in, const int* in_sizes, int n_in,
                              void* d_out, int out_size, void* d_ws, size_t ws_size,
                              hipStream_t stream) {
  const float* x = (const float*)d_in[0];
  const int* ei = (const int*)d_in[1];
  const float* msg_W1 = (const float*)d_in[2];
  const float* msg_b1 = (const float*)d_in[3];
  const float* msg_W2 = (const float*)d_in[4];
  const float* msg_b2 = (const float*)d_in[5];
  const float* upd_W1 = (const float*)d_in[6];
  const float* upd_b1 = (const float*)d_in[7];
  const float* upd_W2 = (const float*)d_in[8];
  const float* upd_b2 = (const float*)d_in[9];
  const float* att_W1 = (const float*)d_in[10];
  const float* att_b1 = (const float*)d_in[11];
  const float* att_W2 = (const float*)d_in[12];
  const float* att_b2 = (const float*)d_in[13];
  const float* glb_W = (const float*)d_in[14];
  const float* glb_b = (const float*)d_in[15];

  const int N = in_sizes[0] / DD;
  const int E = in_sizes[1] / 2;
  const int* src = ei;
  const int* dst = ei + E;

  float* out = (float*)d_out;
  float* aggH = (float*)d_ws;                  // N*128 f32
  float* aggA = aggH + (size_t)N * DD;         // N
  float* colsum = aggA + N;                    // 128
  float* g = colsum + DD;                      // 128
  float* W2U = g + DD;                         // 16384 f32
  float* v2 = W2U + 16384;                     // 128 f32
  short* WbigF = (short*)(v2 + DD);            // 131072 shorts
  short* U1F = WbigF + 131072;                 // 65536
  short* U2F = U1F + 65536;                    // 32768
  int* bsum = (int*)(U2F + 32768);             // 64 ints
  int* rowptr = bsum + 64;                     // N+1 ints
  int* sortedSrc = rowptr + ((N + 1 + 3) & ~3);
  _Float16* Z = (_Float16*)(sortedSrc + ((E + 3) & ~3));  // N*512 fp16
  int* cursor = (int*)aggH;                    // overlay during sort phase only

  wprep_kernel<<<65, 256, 0, stream>>>(msg_W2, msg_b2, upd_W1, W2U, v2);
  conv_kernel<<<112, 256, 0, stream>>>(msg_W1, att_W1, upd_W1, upd_W2, W2U,
                                       WbigF, U1F, U2F);
  zero128_kernel<<<1, 128, 0, stream>>>(colsum);
  colsum_kernel<<<256, 256, 0, stream>>>(x, colsum, N);
  glb_kernel<<<1, 128, 0, stream>>>(colsum, glb_W, glb_b, g, 1.0f / (float)N);

  // CSR build (edges identical both steps -> sort once per launch)
  hipMemsetAsync(rowptr, 0, (size_t)(N + 1) * sizeof(int), stream);
  hist_kernel<<<1024, 256, 0, stream>>>(dst, rowptr, E);
  const int nscan = N + 1;
  const int nb = (nscan + 1023) / 1024;
  scan1_kernel<<<nb, 1024, 0, stream>>>(rowptr, bsum, nscan);
  scan2_kernel<<<1, 1024, 0, stream>>>(bsum, nb);
  if (nb > 1) scan3_kernel<<<nb - 1, 1024, 0, stream>>>(rowptr, bsum, nscan);
  hipMemcpyAsync(cursor, rowptr, (size_t)N * sizeof(int), hipMemcpyDeviceToDevice, stream);
  scatter_kernel<<<1024, 256, 0, stream>>>(src, dst, cursor, sortedSrc, E);

  const int zgrid = (N + 31) / 32;
  const int agrid = (N + 7) / 8;
  const int ngrid = (N + 63) / 64;

  // step 0
  zprep_kernel<<<zgrid, 256, 0, stream>>>(x, WbigF, msg_b1, att_b1, Z, N);
  aggcsr_kernel<<<agrid, 256, 0, stream>>>(Z, rowptr, sortedSrc, att_W2, att_b2,
                                           aggH, aggA, N);
  node_mfma_kernel<1><<<ngrid, 256, 0, stream>>>(x, aggH, aggA, v2, U1F, U2F,
                                                 upd_b1, upd_b2, g, out, N,
                                                 WbigF, msg_b1, att_b1, Z);
  // step 1
  aggcsr_kernel<<<agrid, 256, 0, stream>>>(Z, rowptr, sortedSrc, att_W2, att_b2,
                                           aggH, aggA, N);
  node_mfma_kernel<0><<<ngrid, 256, 0, stream>>>(out, aggH, aggA, v2, U1F, U2F,
                                                 upd_b1, upd_b2, g, out, N,
                                                 WbigF, msg_b1, att_b1, Z);
}

// Round 10
// 509.015 us; speedup vs baseline: 1.0209x; 1.0209x over previous
//
#include <hip/hip_runtime.h>
#include <math.h>

#define DD 128

typedef __attribute__((ext_vector_type(8))) short short8;   // 8 x bf16 bits
typedef __attribute__((ext_vector_type(4))) float f32x4;
typedef __attribute__((ext_vector_type(4))) _Float16 f16x4;

__device__ inline short bf16hi(float x) {
  unsigned u = __float_as_uint(x);
  unsigned r = u + 0x7fffu + ((u >> 16) & 1u);  // RTNE
  return (short)(r >> 16);
}
__device__ inline float bf16tof(short h) {
  return __uint_as_float(((unsigned)(unsigned short)h) << 16);
}
__device__ inline void split2(float x, short& hi, short& lo) {  // RTNE (weights only)
  hi = bf16hi(x);
  float rem = x - bf16tof(hi);
  lo = bf16hi(rem);
}
__device__ inline void splitT(float x, short& hi, short& lo) {  // truncation (cheap)
  unsigned u = __float_as_uint(x);
  hi = (short)(u >> 16);
  float rem = x - __uint_as_float(u & 0xffff0000u);
  lo = (short)(__float_as_uint(rem) >> 16);
}

// ---------------- small helper kernels ----------------
__global__ __launch_bounds__(128) void zero128_kernel(float* p) { p[threadIdx.x] = 0.f; }

__global__ __launch_bounds__(256) void colsum_kernel(const float* __restrict__ x,
                                                     float* __restrict__ colsum, int N) {
  int col = threadIdx.x & 127;
  int part = (blockIdx.x * blockDim.x + threadIdx.x) >> 7;
  int nparts = (gridDim.x * blockDim.x) >> 7;
  float s = 0.f;
  for (int r = part; r < N; r += nparts) s += x[(size_t)r * DD + col];
  atomicAdd(&colsum[col], s);
}

__global__ __launch_bounds__(128) void glb_kernel(const float* __restrict__ colsum,
                                                  const float* __restrict__ glb_W,
                                                  const float* __restrict__ glb_b,
                                                  float* __restrict__ g, float invN) {
  __shared__ float m[DD];
  int j = threadIdx.x;
  m[j] = colsum[j] * invN;
  __syncthreads();
  float s = glb_b[j];
#pragma unroll 8
  for (int k = 0; k < DD; ++k) s = fmaf(m[k], glb_W[k * DD + j], s);
  g[j] = fmaxf(s, 0.f);
}

// W2U = msg_W2 @ upd_W1[128:256] (128x128), v2 = msg_b2 @ upd_W1[128:256] (128)
__global__ __launch_bounds__(256) void wprep_kernel(const float* __restrict__ msg_W2,
                                                    const float* __restrict__ msg_b2,
                                                    const float* __restrict__ upd_W1,
                                                    float* __restrict__ W2U,
                                                    float* __restrict__ v2) {
  int o = blockIdx.x * 256 + threadIdx.x;
  if (o < 16384) {
    int r = o >> 7, c = o & 127;
    float s = 0.f;
#pragma unroll 8
    for (int j = 0; j < 128; ++j) s = fmaf(msg_W2[r * 128 + j], upd_W1[(128 + j) * 128 + c], s);
    W2U[o] = s;
  } else if (o < 16512) {
    int c = o - 16384;
    float s = 0.f;
#pragma unroll 8
    for (int j = 0; j < 128; ++j) s = fmaf(msg_b2[j], upd_W1[(128 + j) * 128 + c], s);
    v2[c] = s;
  }
}

// ---------------- CSR build: histogram -> parallel scan -> scatter ----------------
__global__ __launch_bounds__(256) void hist_kernel(const int* __restrict__ dst,
                                                   int* __restrict__ rowptr, int E) {
  for (int e = blockIdx.x * blockDim.x + threadIdx.x; e < E; e += gridDim.x * blockDim.x)
    atomicAdd(&rowptr[dst[e] + 1], 1);
}

__global__ __launch_bounds__(1024) void scan1_kernel(int* __restrict__ a,
                                                     int* __restrict__ bsum,
                                                     int* __restrict__ cursor, int n) {
  __shared__ int buf[1024];
  const int tid = threadIdx.x;
  int i = blockIdx.x * 1024 + tid;
  buf[tid] = (i < n) ? a[i] : 0;
  __syncthreads();
#pragma unroll
  for (int off = 1; off < 1024; off <<= 1) {
    int t = (tid >= off) ? buf[tid - off] : 0;
    __syncthreads();
    buf[tid] += t;
    __syncthreads();
  }
  if (i < n) {
    a[i] = buf[tid];
    if (blockIdx.x == 0) cursor[i] = buf[tid];  // block 0 has no pending offset
  }
  if (tid == 1023) bsum[blockIdx.x] = buf[1023];
}

__global__ __launch_bounds__(1024) void scan2_kernel(int* __restrict__ a, int n) {
  __shared__ int buf[1024];
  const int tid = threadIdx.x;
  buf[tid] = (tid < n) ? a[tid] : 0;
  __syncthreads();
#pragma unroll
  for (int off = 1; off < 1024; off <<= 1) {
    int t = (tid >= off) ? buf[tid - off] : 0;
    __syncthreads();
    buf[tid] += t;
    __syncthreads();
  }
  if (tid < n) a[tid] = buf[tid];
}

__global__ __launch_bounds__(1024) void scan3_kernel(int* __restrict__ a,
                                                     const int* __restrict__ bsum,
                                                     int* __restrict__ cursor, int n) {
  int b = blockIdx.x + 1;
  int i = b * 1024 + threadIdx.x;
  if (i < n) {
    int v = a[i] + bsum[b - 1];
    a[i] = v;
    cursor[i] = v;
  }
}

__global__ __launch_bounds__(256) void scatter_kernel(const int* __restrict__ src,
                                                      const int* __restrict__ dst,
                                                      int* __restrict__ cursor,
                                                      int* __restrict__ sortedSrc, int E) {
  for (int e = blockIdx.x * blockDim.x + threadIdx.x; e < E; e += gridDim.x * blockDim.x) {
    int pos = atomicAdd(&cursor[dst[e]], 1);
    sortedSrc[pos] = src[e];
  }
}

// ---------------- weight prep: all frag-major hi/lo ----------------
__global__ __launch_bounds__(256) void conv_kernel(
    const float* __restrict__ msg_W1, const float* __restrict__ att_W1,
    const float* __restrict__ upd_W1, const float* __restrict__ upd_W2,
    const float* __restrict__ W2U,
    short* __restrict__ WbigF, short* __restrict__ U1F, short* __restrict__ U2F) {
  int i = blockIdx.x * 256 + threadIdx.x;  // 0 .. 28671
  if (i < 16384) {
    int lane = i & 63, p = (i >> 6) & 1, n = (i >> 7) & 31, c = i >> 12;
    int col = n * 16 + (lane & 15);
#pragma unroll
    for (int j = 0; j < 8; ++j) {
      int k = c * 32 + ((lane >> 4) & 3) * 8 + j;
      float v;
      if (col < 128)      v = msg_W1[k * 128 + col];
      else if (col < 256) v = att_W1[k * 128 + (col - 128)];
      else if (col < 384) v = msg_W1[(k + 128) * 128 + (col - 256)];
      else                v = att_W1[(k + 128) * 128 + (col - 384)];
      short hi, lo; splitT(v, hi, lo);
      WbigF[(size_t)i * 8 + j] = p ? lo : hi;
    }
  } else if (i < 24576) {
    int gI = i - 16384;  // 8192 entries
    int lane = gI & 63, p = (gI >> 6) & 1, n = (gI >> 7) & 7, c = gI >> 10;  // c in [0,8)
    int col = n * 16 + (lane & 15);
#pragma unroll
    for (int j = 0; j < 8; ++j) {
      int k = c * 32 + ((lane >> 4) & 3) * 8 + j;
      float v = (k < 128) ? upd_W1[k * 128 + col] : W2U[(k - 128) * 128 + col];
      short hi, lo; split2(v, hi, lo);
      U1F[(size_t)gI * 8 + j] = p ? lo : hi;
    }
  } else {
    int gI = i - 24576;  // 4096 entries
    int lane = gI & 63, p = (gI >> 6) & 1, n = (gI >> 7) & 7, c = gI >> 10;  // c in [0,4)
    int col = n * 16 + (lane & 15);
#pragma unroll
    for (int j = 0; j < 8; ++j) {
      int k = c * 32 + ((lane >> 4) & 3) * 8 + j;
      float v = upd_W2[k * 128 + col];
      short hi, lo; split2(v, hi, lo);
      U2F[(size_t)gI * 8 + j] = p ? lo : hi;
    }
  }
}

// ---------------- Z-prep GEMM (step 0): Z[N x 512] fp16 = h @ Wbig + bias ----
__global__ __launch_bounds__(256, 3) void zprep_kernel(
    const float* __restrict__ h, const short* __restrict__ WbigF,
    const float* __restrict__ msg_b1, const float* __restrict__ att_b1,
    _Float16* __restrict__ Z, int N) {
  const int tid = threadIdx.x;
  const int w = tid >> 6;
  const int lane = tid & 63;
  const int m16 = lane & 15, q = lane >> 4;
  const int r0 = blockIdx.x * 32;

  f32x4 acc[2][8];
#pragma unroll
  for (int nt = 0; nt < 8; ++nt) {
    int col = w * 128 + nt * 16 + m16;
    float b = (col < 128) ? msg_b1[col] : ((col < 256) ? att_b1[col - 128] : 0.f);
    acc[0][nt] = (f32x4){b, b, b, b};
    acc[1][nt] = (f32x4){b, b, b, b};
  }

  for (int c = 0; c < 4; ++c) {
    short8 ah[2], al[2];
#pragma unroll
    for (int mt = 0; mt < 2; ++mt) {
      int row = min(r0 + mt * 16 + m16, N - 1);
      const float* p = h + (size_t)row * DD + c * 32 + q * 8;
      float4 v0 = *(const float4*)p;
      float4 v1 = *(const float4*)(p + 4);
      float f[8] = {v0.x, v0.y, v0.z, v0.w, v1.x, v1.y, v1.z, v1.w};
#pragma unroll
      for (int j = 0; j < 8; ++j) { short hi, lo; splitT(f[j], hi, lo); ah[mt][j] = hi; al[mt][j] = lo; }
    }
#pragma unroll
    for (int nt = 0; nt < 8; ++nt) {
      int ng = w * 8 + nt;
      const short* bp = WbigF + ((size_t)((c * 32 + ng) * 2) * 64 + lane) * 8;
      short8 bh = *(const short8*)bp;
      short8 bl = *(const short8*)(bp + 512);
#pragma unroll
      for (int mt = 0; mt < 2; ++mt) {
        acc[mt][nt] = __builtin_amdgcn_mfma_f32_16x16x32_bf16(ah[mt], bh, acc[mt][nt], 0, 0, 0);
        acc[mt][nt] = __builtin_amdgcn_mfma_f32_16x16x32_bf16(al[mt], bh, acc[mt][nt], 0, 0, 0);
        acc[mt][nt] = __builtin_amdgcn_mfma_f32_16x16x32_bf16(ah[mt], bl, acc[mt][nt], 0, 0, 0);
      }
    }
  }

#pragma unroll
  for (int mt = 0; mt < 2; ++mt)
#pragma unroll
    for (int r = 0; r < 4; ++r) {
      int row = r0 + mt * 16 + q * 4 + r;
      if (row < N) {
#pragma unroll
        for (int nt = 0; nt < 8; ++nt) {
          int col = w * 128 + nt * 16 + m16;
          Z[(size_t)row * 512 + col] = (_Float16)acc[mt][nt][r];
        }
      }
    }
}

// ---------------- CSR aggregation (no atomics; all-fp16 Z) ----------------
__global__ __launch_bounds__(256) void aggcsr_kernel(
    const _Float16* __restrict__ Z, const int* __restrict__ rowptr,
    const int* __restrict__ sortedSrc, const float* __restrict__ att_W2,
    const float* __restrict__ att_b2, float* __restrict__ aggH,
    float* __restrict__ aggA, int N) {
  const int node = blockIdx.x * 8 + (threadIdx.x >> 5);
  const int c = threadIdx.x & 31;
  if (node >= N) return;

  const float4 aw = *(const float4*)(att_W2 + 4 * c);
  const float ab2 = att_b2[0];
  const _Float16* Zn = Z + (size_t)node * 512 + 256;
  f16x4 dmh = *(const f16x4*)(Zn + 4 * c);
  f16x4 dah = *(const f16x4*)(Zn + 128 + 4 * c);
  float dm[4] = {(float)dmh[0], (float)dmh[1], (float)dmh[2], (float)dmh[3]};
  float da[4] = {(float)dah[0], (float)dah[1], (float)dah[2], (float)dah[3]};

  float aH0 = 0.f, aH1 = 0.f, aH2 = 0.f, aH3 = 0.f, aA = 0.f;
  const int b = rowptr[node], e = rowptr[node + 1];

  int i = b;
  for (; i + 1 < e; i += 2) {
    int s0 = sortedSrc[i], s1 = sortedSrc[i + 1];
    const _Float16* Z0 = Z + (size_t)s0 * 512 + 4 * c;
    const _Float16* Z1 = Z + (size_t)s1 * 512 + 4 * c;
    f16x4 m0 = *(const f16x4*)Z0, a0 = *(const f16x4*)(Z0 + 128);
    f16x4 m1 = *(const f16x4*)Z1, a1 = *(const f16x4*)(Z1 + 128);

    float h0[4], h1[4];
    h0[0] = fmaxf((float)m0[0] + dm[0], 0.f); h0[1] = fmaxf((float)m0[1] + dm[1], 0.f);
    h0[2] = fmaxf((float)m0[2] + dm[2], 0.f); h0[3] = fmaxf((float)m0[3] + dm[3], 0.f);
    h1[0] = fmaxf((float)m1[0] + dm[0], 0.f); h1[1] = fmaxf((float)m1[1] + dm[1], 0.f);
    h1[2] = fmaxf((float)m1[2] + dm[2], 0.f); h1[3] = fmaxf((float)m1[3] + dm[3], 0.f);

    float p0 = fmaf(fmaxf((float)a0[0] + da[0], 0.f), aw.x,
               fmaf(fmaxf((float)a0[1] + da[1], 0.f), aw.y,
               fmaf(fmaxf((float)a0[2] + da[2], 0.f), aw.z,
                    fmaxf((float)a0[3] + da[3], 0.f) * aw.w)));
    float p1 = fmaf(fmaxf((float)a1[0] + da[0], 0.f), aw.x,
               fmaf(fmaxf((float)a1[1] + da[1], 0.f), aw.y,
               fmaf(fmaxf((float)a1[2] + da[2], 0.f), aw.z,
                    fmaxf((float)a1[3] + da[3], 0.f) * aw.w)));
#pragma unroll
    for (int off = 1; off < 32; off <<= 1) {
      p0 += __shfl_xor(p0, off);
      p1 += __shfl_xor(p1, off);
    }
    float t0 = 1.f / (1.f + expf(-(p0 + ab2)));
    float t1 = 1.f / (1.f + expf(-(p1 + ab2)));
    aA += t0 + t1;
    aH0 = fmaf(t0, h0[0], fmaf(t1, h1[0], aH0));
    aH1 = fmaf(t0, h0[1], fmaf(t1, h1[1], aH1));
    aH2 = fmaf(t0, h0[2], fmaf(t1, h1[2], aH2));
    aH3 = fmaf(t0, h0[3], fmaf(t1, h1[3], aH3));
  }
  if (i < e) {
    int s0 = sortedSrc[i];
    const _Float16* Z0 = Z + (size_t)s0 * 512 + 4 * c;
    f16x4 m0 = *(const f16x4*)Z0, a0 = *(const f16x4*)(Z0 + 128);
    float h00 = fmaxf((float)m0[0] + dm[0], 0.f), h01 = fmaxf((float)m0[1] + dm[1], 0.f);
    float h02 = fmaxf((float)m0[2] + dm[2], 0.f), h03 = fmaxf((float)m0[3] + dm[3], 0.f);
    float p0 = fmaf(fmaxf((float)a0[0] + da[0], 0.f), aw.x,
               fmaf(fmaxf((float)a0[1] + da[1], 0.f), aw.y,
               fmaf(fmaxf((float)a0[2] + da[2], 0.f), aw.z,
                    fmaxf((float)a0[3] + da[3], 0.f) * aw.w)));
#pragma unroll
    for (int off = 1; off < 32; off <<= 1) p0 += __shfl_xor(p0, off);
    float t0 = 1.f / (1.f + expf(-(p0 + ab2)));
    aA += t0;
    aH0 = fmaf(t0, h00, aH0);
    aH1 = fmaf(t0, h01, aH1);
    aH2 = fmaf(t0, h02, aH2);
    aH3 = fmaf(t0, h03, aH3);
  }

  *(float4*)(aggH + (size_t)node * DD + 4 * c) = (float4){aH0, aH1, aH2, aH3};
  if (c == 0) aggA[node] = aA;
}

// ---------------- node update (row-split waves, 4 blocks/CU) ----------------
// out = relu(h@U1top + aggH@W2U + aggA (x) v2 + upd_b1) @ U2 + upd_b2 + h + g
// Wave w owns rows [16w,16w+16), all 128 cols. B frag-major from global (L2-hot).
// DOZ: additionally Z = out @ Wbig for this block's 64 rows (fp16), wave w -> 128 cols.
template <int DOZ>
__global__ __launch_bounds__(256, 4) void node_mfma_kernel(
    const float* __restrict__ h, const float* __restrict__ aggH,
    const float* __restrict__ aggA, const float* __restrict__ v2,
    const short* __restrict__ U1F, const short* __restrict__ U2F,
    const float* __restrict__ upd_b1, const float* __restrict__ upd_b2,
    const float* __restrict__ g, float* __restrict__ out, int N,
    const short* __restrict__ WbigF, const float* __restrict__ msg_b1,
    const float* __restrict__ att_b1, _Float16* __restrict__ Z) {
  __shared__ __align__(16) char smemraw[33792];
  unsigned* HID32 = (unsigned*)smemraw;  // 64 x 132 packed (hi<<16 | lo)
  float* OUTs = (float*)smemraw;         // 64 x 132 fp32 (DOZ overlay)

  const int tid = threadIdx.x;
  const int wave = tid >> 6;
  const int lane = tid & 63;
  const int m16 = lane & 15;
  const int q = lane >> 4;

  const int n0 = blockIdx.x * 64;
  const int nA = n0 + wave * 16 + m16;
  const int nAc = min(nA, N - 1);

  // A-frags: rows = this wave's 16 rows; k 0:128 from h, 128:256 from aggH
  short8 a1h[8], a1l[8];
  {
    const float* rs = h + (size_t)nAc * DD;
    const float* rd = aggH + (size_t)nAc * DD;
#pragma unroll
    for (int t = 0; t < 8; ++t) {
      const float* base = ((t < 4) ? (rs + t * 32) : (rd + (t - 4) * 32)) + q * 8;
      float4 v0 = *(const float4*)(base);
      float4 v1 = *(const float4*)(base + 4);
      float f[8] = {v0.x, v0.y, v0.z, v0.w, v1.x, v1.y, v1.z, v1.w};
#pragma unroll
      for (int j = 0; j < 8; ++j) { short hi, lo; splitT(f[j], hi, lo); a1h[t][j] = hi; a1l[t][j] = lo; }
    }
  }

  f32x4 acc[8];
#pragma unroll
  for (int n = 0; n < 8; ++n) {
    float b = upd_b1[n * 16 + m16];
    acc[n] = (f32x4){b, b, b, b};
  }

#pragma unroll
  for (int c = 0; c < 8; ++c) {
#pragma unroll
    for (int n = 0; n < 8; ++n) {
      const short* bp = U1F + ((size_t)((c * 8 + n) * 2) * 64 + lane) * 8;
      short8 bh = *(const short8*)bp;
      short8 bl = *(const short8*)(bp + 512);
      acc[n] = __builtin_amdgcn_mfma_f32_16x16x32_bf16(a1h[c], bh, acc[n], 0, 0, 0);
      acc[n] = __builtin_amdgcn_mfma_f32_16x16x32_bf16(a1l[c], bh, acc[n], 0, 0, 0);
      acc[n] = __builtin_amdgcn_mfma_f32_16x16x32_bf16(a1h[c], bl, acc[n], 0, 0, 0);
    }
  }

  // fold in aggA (x) v2, relu, pack to LDS
  {
    float aAv[4];
#pragma unroll
    for (int r = 0; r < 4; ++r) aAv[r] = aggA[min(n0 + wave * 16 + q * 4 + r, N - 1)];
#pragma unroll
    for (int n = 0; n < 8; ++n) {
      float vv = v2[n * 16 + m16];
      int col = n * 16 + m16;
#pragma unroll
      for (int r = 0; r < 4; ++r) {
        float v = fmaxf(fmaf(aAv[r], vv, acc[n][r]), 0.f);
        short hi, lo; splitT(v, hi, lo);
        HID32[(wave * 16 + q * 4 + r) * 132 + col] =
            (((unsigned)(unsigned short)hi) << 16) | (unsigned)(unsigned short)lo;
      }
    }
  }
  __syncthreads();

  short8 a2h[4], a2l[4];
  {
    int mrow = wave * 16 + m16;
#pragma unroll
    for (int t = 0; t < 4; ++t) {
      const unsigned* hp = &HID32[mrow * 132 + t * 32 + q * 8];
      uint4 u0 = *(const uint4*)hp;
      uint4 u1 = *(const uint4*)(hp + 4);
      unsigned u[8] = {u0.x, u0.y, u0.z, u0.w, u1.x, u1.y, u1.z, u1.w};
#pragma unroll
      for (int j = 0; j < 8; ++j) {
        a2h[t][j] = (short)(u[j] >> 16);
        a2l[t][j] = (short)(u[j] & 0xffffu);
      }
    }
  }

  f32x4 acc2[8];
#pragma unroll
  for (int n = 0; n < 8; ++n) {
    float b = upd_b2[n * 16 + m16];
    acc2[n] = (f32x4){b, b, b, b};
  }

#pragma unroll
  for (int t = 0; t < 4; ++t) {
#pragma unroll
    for (int n = 0; n < 8; ++n) {
      const short* bp = U2F + ((size_t)((t * 8 + n) * 2) * 64 + lane) * 8;
      short8 bh = *(const short8*)bp;
      short8 bl = *(const short8*)(bp + 512);
      acc2[n] = __builtin_amdgcn_mfma_f32_16x16x32_bf16(a2h[t], bh, acc2[n], 0, 0, 0);
      acc2[n] = __builtin_amdgcn_mfma_f32_16x16x32_bf16(a2l[t], bh, acc2[n], 0, 0, 0);
      acc2[n] = __builtin_amdgcn_mfma_f32_16x16x32_bf16(a2h[t], bl, acc2[n], 0, 0, 0);
    }
  }

  // epilogue: out = acc2 + h + g  (DOZ: stage into LDS for fused Z-prep)
  if (DOZ) __syncthreads();  // all HID32 reads done before OUTs overlay
#pragma unroll
  for (int r = 0; r < 4; ++r) {
    int rowN = n0 + wave * 16 + q * 4 + r;
    int rc = min(rowN, N - 1);
#pragma unroll
    for (int n = 0; n < 8; ++n) {
      int col = n * 16 + m16;
      float v = acc2[n][r] + h[(size_t)rc * DD + col] + g[col];
      if (DOZ) OUTs[(wave * 16 + q * 4 + r) * 132 + col] = v;
      if (rowN < N) out[(size_t)rowN * DD + col] = v;
    }
  }

  if (DOZ) {
    __syncthreads();
    // Z-GEMM for this block's 64 rows: wave w -> cols [128w, 128w+128)
#pragma unroll
    for (int half = 0; half < 2; ++half) {
      f32x4 zacc[4][4];
#pragma unroll
      for (int nt = 0; nt < 4; ++nt) {
        int col = wave * 128 + half * 64 + nt * 16 + m16;
        float b = (col < 128) ? msg_b1[col] : ((col < 256) ? att_b1[col - 128] : 0.f);
#pragma unroll
        for (int mt = 0; mt < 4; ++mt) zacc[mt][nt] = (f32x4){b, b, b, b};
      }
      for (int c = 0; c < 4; ++c) {
        short8 ah[4], al[4];
#pragma unroll
        for (int mt = 0; mt < 4; ++mt) {
          const float* p = OUTs + (mt * 16 + m16) * 132 + c * 32 + q * 8;
          float4 v0 = *(const float4*)p;
          float4 v1 = *(const float4*)(p + 4);
          float f[8] = {v0.x, v0.y, v0.z, v0.w, v1.x, v1.y, v1.z, v1.w};
#pragma unroll
          for (int j = 0; j < 8; ++j) {
            short hi, lo; splitT(f[j], hi, lo); ah[mt][j] = hi; al[mt][j] = lo;
          }
        }
#pragma unroll
        for (int nt = 0; nt < 4; ++nt) {
          int ng = wave * 8 + half * 4 + nt;
          const short* bp = WbigF + ((size_t)((c * 32 + ng) * 2) * 64 + lane) * 8;
          short8 bh = *(const short8*)bp;
          short8 bl = *(const short8*)(bp + 512);
#pragma unroll
          for (int mt = 0; mt < 4; ++mt) {
            zacc[mt][nt] = __builtin_amdgcn_mfma_f32_16x16x32_bf16(ah[mt], bh, zacc[mt][nt], 0, 0, 0);
            zacc[mt][nt] = __builtin_amdgcn_mfma_f32_16x16x32_bf16(al[mt], bh, zacc[mt][nt], 0, 0, 0);
            zacc[mt][nt] = __builtin_amdgcn_mfma_f32_16x16x32_bf16(ah[mt], bl, zacc[mt][nt], 0, 0, 0);
          }
        }
      }
#pragma unroll
      for (int mt = 0; mt < 4; ++mt)
#pragma unroll
        for (int r = 0; r < 4; ++r) {
          int row = n0 + mt * 16 + q * 4 + r;
          if (row < N) {
#pragma unroll
            for (int nt = 0; nt < 4; ++nt) {
              int col = wave * 128 + half * 64 + nt * 16 + m16;
              Z[(size_t)row * 512 + col] = (_Float16)zacc[mt][nt][r];
            }
          }
        }
    }
  }
}

extern "C" void kernel_launch(void* const* d_in, const int* in_sizes, int n_in,
                              void* d_out, int out_size, void* d_ws, size_t ws_size,
                              hipStream_t stream) {
  const float* x = (const float*)d_in[0];
  const int* ei = (const int*)d_in[1];
  const float* msg_W1 = (const float*)d_in[2];
  const float* msg_b1 = (const float*)d_in[3];
  const float* msg_W2 = (const float*)d_in[4];
  const float* msg_b2 = (const float*)d_in[5];
  const float* upd_W1 = (const float*)d_in[6];
  const float* upd_b1 = (const float*)d_in[7];
  const float* upd_W2 = (const float*)d_in[8];
  const float* upd_b2 = (const float*)d_in[9];
  const float* att_W1 = (const float*)d_in[10];
  const float* att_b1 = (const float*)d_in[11];
  const float* att_W2 = (const float*)d_in[12];
  const float* att_b2 = (const float*)d_in[13];
  const float* glb_W = (const float*)d_in[14];
  const float* glb_b = (const float*)d_in[15];

  const int N = in_sizes[0] / DD;
  const int E = in_sizes[1] / 2;
  const int* src = ei;
  const int* dst = ei + E;

  float* out = (float*)d_out;
  float* aggH = (float*)d_ws;                  // N*128 f32
  float* aggA = aggH + (size_t)N * DD;         // N
  float* colsum = aggA + N;                    // 128
  float* g = colsum + DD;                      // 128
  float* W2U = g + DD;                         // 16384 f32
  float* v2 = W2U + 16384;                     // 128 f32
  short* WbigF = (short*)(v2 + DD);            // 131072 shorts
  short* U1F = WbigF + 131072;                 // 65536
  short* U2F = U1F + 65536;                    // 32768
  int* bsum = (int*)(U2F + 32768);             // 64 ints
  int* rowptr = bsum + 64;                     // N+1 ints
  int* sortedSrc = rowptr + ((N + 1 + 3) & ~3);
  _Float16* Z = (_Float16*)(sortedSrc + ((E + 3) & ~3));  // N*512 fp16
  int* cursor = (int*)aggH;                    // overlay during sort phase only

  wprep_kernel<<<65, 256, 0, stream>>>(msg_W2, msg_b2, upd_W1, W2U, v2);
  conv_kernel<<<112, 256, 0, stream>>>(msg_W1, att_W1, upd_W1, upd_W2, W2U,
                                       WbigF, U1F, U2F);
  zero128_kernel<<<1, 128, 0, stream>>>(colsum);
  colsum_kernel<<<256, 256, 0, stream>>>(x, colsum, N);
  glb_kernel<<<1, 128, 0, stream>>>(colsum, glb_W, glb_b, g, 1.0f / (float)N);

  // CSR build (edges identical both steps -> sort once per launch)
  hipMemsetAsync(rowptr, 0, (size_t)(N + 1) * sizeof(int), stream);
  hist_kernel<<<1024, 256, 0, stream>>>(dst, rowptr, E);
  const int nscan = N + 1;
  const int nb = (nscan + 1023) / 1024;
  scan1_kernel<<<nb, 1024, 0, stream>>>(rowptr, bsum, cursor, nscan);
  scan2_kernel<<<1, 1024, 0, stream>>>(bsum, nb);
  if (nb > 1) scan3_kernel<<<nb - 1, 1024, 0, stream>>>(rowptr, bsum, cursor, nscan);
  scatter_kernel<<<1024, 256, 0, stream>>>(src, dst, cursor, sortedSrc, E);

  const int zgrid = (N + 31) / 32;
  const int agrid = (N + 7) / 8;
  const int ngrid = (N + 63) / 64;

  // step 0
  zprep_kernel<<<zgrid, 256, 0, stream>>>(x, WbigF, msg_b1, att_b1, Z, N);
  aggcsr_kernel<<<agrid, 256, 0, stream>>>(Z, rowptr, sortedSrc, att_W2, att_b2,
                                           aggH, aggA, N);
  node_mfma_kernel<1><<<ngrid, 256, 0, stream>>>(x, aggH, aggA, v2, U1F, U2F,
                                                 upd_b1, upd_b2, g, out, N,
                                                 WbigF, msg_b1, att_b1, Z);
  // step 1
  aggcsr_kernel<<<agrid, 256, 0, stream>>>(Z, rowptr, sortedSrc, att_W2, att_b2,
                                           aggH, aggA, N);
  node_mfma_kernel<0><<<ngrid, 256, 0, stream>>>(out, aggH, aggA, v2, U1F, U2F,
                                                 upd_b1, upd_b2, g, out, N,
                                                 WbigF, msg_b1, att_b1, Z);
}